// Round 6
// baseline (174.697 us; speedup 1.0000x reference)
//
#include <hip/hip_runtime.h>
#include <hip/hip_bf16.h>
#include <stdint.h>

#define N_NODES 2048
#define WORDS   32          // 2048/64 bitset words per row
#define LABELS  16
#define FILTERS 16
#define FNODES  8
#define MAX_EGO 128
#define WL_LEVELS 4

typedef unsigned long long u64;

__device__ __forceinline__ unsigned mixu(unsigned h) {
    h ^= h >> 16; h *= 0x7FEB352Du;
    h ^= h >> 15; h *= 0x846CA68Bu;
    h ^= h >> 16;
    return h;
}

// K1: block i builds Adense row i by scanning the edge list (no memset, no
// global atomics). Block 0 lanes 0..15 additionally compute the filter-graph
// WL hashes / masks / self_f.
__global__ void __launch_bounds__(64)
build_rows_kernel(const int* __restrict__ ei, int E2, u64* __restrict__ Adense,
                  const float* __restrict__ Af, const float* __restrict__ Xf,
                  unsigned* __restrict__ hfg, unsigned* __restrict__ fmbg,
                  float* __restrict__ selfg) {
    const int i = blockIdx.x;
    const int lane = threadIdx.x;
    __shared__ unsigned row32[WORDS * 2];
    if (lane < WORDS * 2 - 64) row32[64 + lane] = 0;   // lanes 0..? (WORDS*2=64) -> none
    row32[lane] = 0;                                    // 64 lanes zero 64 words
    __syncthreads();
    for (int e = lane; e < E2; e += 64) {
        int s = ei[e], d = ei[E2 + e];
        if (s == i) atomicOr(&row32[d >> 5], 1u << (d & 31));
        if (d == i) atomicOr(&row32[s >> 5], 1u << (s & 31));
    }
    __syncthreads();
    if (lane < WORDS) {
        u64 v = (u64)row32[2 * lane] | ((u64)row32[2 * lane + 1] << 32);
        Adense[(size_t)i * WORDS + lane] = v;
    }

    if (i == 0 && lane < FILTERS) {
        // ---- filters: CC mask, labels, 4 WL levels, self_f -> global ws ----
        int f = lane;
        const float* Aff = Af + (size_t)f * FNODES * FNODES;
        unsigned row[FNODES];
        for (int m = 0; m < FNODES; ++m) {
            unsigned r = 0;
            for (int j = 0; j < FNODES; ++j)
                if (Aff[m * FNODES + j] > 0.f) r |= 1u << j;
            row[m] = r;
        }
        const float* Xff = Xf + (size_t)f * FNODES * LABELS;
        unsigned lab[FNODES];
        for (int m = 0; m < FNODES; ++m) {
            const float* xr = Xff + m * LABELS;
            float best = xr[0]; int bi = 0;
            for (int c = 1; c < LABELS; ++c) { float v = xr[c]; if (v > best) { best = v; bi = c; } }
            lab[m] = (unsigned)(bi + 1);
        }
        int lbl[FNODES];
        for (int m = 0; m < FNODES; ++m) lbl[m] = m;
        for (int it = 0; it < FNODES; ++it) {
            int nb[FNODES];
            for (int m = 0; m < FNODES; ++m) {
                int mn = FNODES;
                for (int j = 0; j < FNODES; ++j)
                    if ((row[m] >> j) & 1) mn = min(mn, lbl[j]);
                nb[m] = mn;
            }
            for (int m = 0; m < FNODES; ++m) lbl[m] = min(lbl[m], nb[m]);
        }
        int cnt[FNODES];
        for (int m = 0; m < FNODES; ++m) {
            int c = 0;
            for (int j = 0; j < FNODES; ++j) c += (lbl[j] == lbl[m]);
            cnt[m] = c;
        }
        int best = 0;
        for (int m = 1; m < FNODES; ++m) if (cnt[m] > cnt[best]) best = m;
        unsigned fm = 0;
        for (int m = 0; m < FNODES; ++m) if (lbl[m] == lbl[best]) fm |= 1u << m;
        fmbg[f] = fm;
        unsigned brow[FNODES];
        for (int m = 0; m < FNODES; ++m) brow[m] = ((fm >> m) & 1) ? (row[m] & fm) : 0u;
        unsigned hh[FNODES];
        for (int m = 0; m < FNODES; ++m) hh[m] = mixu(lab[m]);
        float sf = 0.f;
        for (int t = 0; t < WL_LEVELS; ++t) {
            if (t > 0) {
                unsigned mx[FNODES], nh[FNODES];
                for (int m = 0; m < FNODES; ++m) mx[m] = mixu(hh[m]);
                for (int m = 0; m < FNODES; ++m) {
                    unsigned msg = 0;
                    for (int j = 0; j < FNODES; ++j)
                        if ((brow[m] >> j) & 1) msg += mx[j];
                    nh[m] = mixu(hh[m] * 0x9E3779B1u + msg);
                }
                for (int m = 0; m < FNODES; ++m) hh[m] = nh[m];
            }
            for (int m = 0; m < FNODES; ++m)
                hfg[t * FILTERS * FNODES + f * FNODES + m] = hh[m];
            int c = 0;
            for (int m = 0; m < FNODES; ++m) if ((fm >> m) & 1)
                for (int j = 0; j < FNODES; ++j) if ((fm >> j) & 1) c += (hh[m] == hh[j]);
            sf += (float)c;
        }
        selfg[f] = sf;
    }
}

// K2: r2[i] = (I|A)^2 row i. Half-waves split neighbor set by word parity,
// merged with shfl_xor(32). (Neighbor diag bits are covered by arow itself.)
__global__ void __launch_bounds__(64)
r2_kernel(const u64* __restrict__ Adense, u64* __restrict__ r2) {
    const int i = blockIdx.x;
    const int lane = threadIdx.x;
    const int w = lane & 31, hwp = lane >> 5;
    __shared__ u64 arow[WORDS];
    if (lane < WORDS) arow[lane] = Adense[(size_t)i * WORDS + lane];
    __syncthreads();
    u64 acc = 0;
    if (hwp == 0) {
        acc = arow[w];
        if ((i >> 6) == w) acc |= 1ull << (i & 63);
    }
    for (int w2 = hwp; w2 < WORDS; w2 += 2) {
        u64 bits = arow[w2];
        while (bits) {
            int b = __ffsll(bits) - 1;
            bits &= bits - 1;
            acc |= Adense[(size_t)((w2 << 6) + b) * WORDS + w];
        }
    }
    acc |= __shfl_xor(acc, 32, 64);
    if (hwp == 0) r2[(size_t)i * WORDS + w] = acc;
}

// K3: one WAVE per seed. Hop 3 fused; compact adjacency; 4 WL levels.
__global__ void __launch_bounds__(64)
ego_kernel(const float* __restrict__ x,
           const u64* __restrict__ Adense,
           const u64* __restrict__ r2,
           const unsigned* __restrict__ hfg, const unsigned* __restrict__ fmbg,
           const float* __restrict__ selfg, float* __restrict__ out) {
    const int i    = blockIdx.x;
    const int lane = threadIdx.x;

    __shared__ u64 arow[WORDS];
    __shared__ u64 mmask[WORDS];
    __shared__ unsigned pfx[WORDS];
    __shared__ unsigned members[MAX_EGO];
    __shared__ __align__(16) unsigned h[MAX_EGO];
    __shared__ unsigned mixed[MAX_EGO];
    __shared__ __align__(16) unsigned adjs[MAX_EGO][4];
    __shared__ unsigned hf_s[WL_LEVELS * FILTERS * FNODES];
    __shared__ unsigned fmb[FILTERS];
    __shared__ float    selff_s[FILTERS];
    __shared__ unsigned cross_sh[FILTERS];
    __shared__ unsigned selfe_sh;

    for (int t = lane; t < WL_LEVELS * FILTERS * FNODES; t += 64) hf_s[t] = hfg[t];
    if (lane < FILTERS) { fmb[lane] = fmbg[lane]; selff_s[lane] = selfg[lane]; }
    #pragma unroll
    for (int t = lane; t < MAX_EGO * 4; t += 64) ((unsigned*)adjs)[t] = 0;
    if (lane < WORDS) arow[lane] = Adense[(size_t)i * WORDS + lane];
    __syncthreads();

    // ---- hop 3 + member mask (seed + 127 smallest-index members) ----
    int S;
    {
        const int w = lane & 31, hwp = lane >> 5;
        u64 v = (hwp == 0) ? r2[(size_t)i * WORDS + w] : 0ull;
        for (int w2 = hwp; w2 < WORDS; w2 += 2) {
            u64 bits = arow[w2];
            while (bits) {
                int b = __ffsll(bits) - 1;
                bits &= bits - 1;
                v |= r2[(size_t)((w2 << 6) + b) * WORDS + w];
            }
        }
        v |= __shfl_xor(v, 32, 64);       // full r3 word w on both halves
        int seedw = i >> 6;
        u64 seedbit = 1ull << (i & 63);
        if (w == seedw) v &= ~seedbit;
        int pc = __popcll(v);
        int incl = pc;
        for (int d = 1; d < 32; d <<= 1) {
            int t2 = __shfl_up(incl, d, 32);
            if (w >= d) incl += t2;
        }
        int excl = incl - pc;
        const int keep = MAX_EGO - 1;
        if (excl >= keep) {
            v = 0;
        } else {
            int allow = keep - excl;
            while (pc > allow) {
                v &= ~(1ull << (63 - __clzll(v)));
                --pc;
            }
        }
        if (w == seedw) v |= seedbit;
        mmask[w] = v;
        int pc2 = __popcll(v);
        int incl2 = pc2;
        for (int d = 1; d < 32; d <<= 1) {
            int t2 = __shfl_up(incl2, d, 32);
            if (w >= d) incl2 += t2;
        }
        int ex2 = incl2 - pc2;
        pfx[w] = (unsigned)ex2;
        u64 vv = v;
        int r = 0;
        while (vv) {
            int b = __ffsll(vv) - 1;
            vv &= vv - 1;
            members[ex2 + r] = (unsigned)((w << 6) + b);   // both halves: same data
            ++r;
        }
        S = __shfl(incl2, 31, 32);        // total within each 32-lane half
    }
    __syncthreads();
    const int s0 = lane, s1 = lane + 64;
    const bool p0 = (s0 < S), p1 = (s1 < S);

    // ---- initial WL labels (argmax16, first-max tie-break), float4 loads ----
    {
        unsigned hl0 = 0, hl1 = 0;
        if (p0) {
            const float4* xr = (const float4*)(x + (size_t)members[s0] * LABELS);
            float4 a0 = xr[0], a1 = xr[1], a2 = xr[2], a3 = xr[3];
            float vv[16] = {a0.x,a0.y,a0.z,a0.w,a1.x,a1.y,a1.z,a1.w,
                            a2.x,a2.y,a2.z,a2.w,a3.x,a3.y,a3.z,a3.w};
            float best = vv[0]; int bi = 0;
            #pragma unroll
            for (int c = 1; c < 16; ++c) { if (vv[c] > best) { best = vv[c]; bi = c; } }
            hl0 = mixu((unsigned)(bi + 1));
        }
        if (p1) {
            const float4* xr = (const float4*)(x + (size_t)members[s1] * LABELS);
            float4 a0 = xr[0], a1 = xr[1], a2 = xr[2], a3 = xr[3];
            float vv[16] = {a0.x,a0.y,a0.z,a0.w,a1.x,a1.y,a1.z,a1.w,
                            a2.x,a2.y,a2.z,a2.w,a3.x,a3.y,a3.z,a3.w};
            float best = vv[0]; int bi = 0;
            #pragma unroll
            for (int c = 1; c < 16; ++c) { if (vv[c] > best) { best = vv[c]; bi = c; } }
            hl1 = mixu((unsigned)(bi + 1));
        }
        if (p0) h[s0] = hl0;
        if (p1) h[s1] = hl1;
    }

    // ---- compact ego adjacency (half-wave per slot, 4-deep load batch) ----
    {
        const int hwp = lane >> 5, wl = lane & 31;
        const u64 mw = mmask[wl];
        const unsigned base = pfx[wl];
        for (int t = hwp; t < S; t += 8) {
            int t1 = t + 2, t2 = t + 4, t3 = t + 6;
            u64 v0 = Adense[(size_t)members[t] * WORDS + wl] & mw;
            u64 v1 = (t1 < S) ? (Adense[(size_t)members[t1] * WORDS + wl] & mw) : 0ull;
            u64 v2 = (t2 < S) ? (Adense[(size_t)members[t2] * WORDS + wl] & mw) : 0ull;
            u64 v3 = (t3 < S) ? (Adense[(size_t)members[t3] * WORDS + wl] & mw) : 0ull;
            while (v0) {
                int b = __ffsll(v0) - 1; v0 &= v0 - 1;
                int slot = (int)base + __popcll(mw & ((1ull << b) - 1));
                atomicOr(&adjs[t][slot >> 5], 1u << (slot & 31));
            }
            while (v1) {
                int b = __ffsll(v1) - 1; v1 &= v1 - 1;
                int slot = (int)base + __popcll(mw & ((1ull << b) - 1));
                atomicOr(&adjs[t1][slot >> 5], 1u << (slot & 31));
            }
            while (v2) {
                int b = __ffsll(v2) - 1; v2 &= v2 - 1;
                int slot = (int)base + __popcll(mw & ((1ull << b) - 1));
                atomicOr(&adjs[t2][slot >> 5], 1u << (slot & 31));
            }
            while (v3) {
                int b = __ffsll(v3) - 1; v3 &= v3 - 1;
                int slot = (int)base + __popcll(mw & ((1ull << b) - 1));
                atomicOr(&adjs[t3][slot >> 5], 1u << (slot & 31));
            }
        }
    }
    __syncthreads();

    // ---- 4 WL levels: refine + cross/self accumulate ----
    unsigned crossReg[FILTERS];
    #pragma unroll
    for (int f = 0; f < FILTERS; ++f) crossReg[f] = 0;
    unsigned selfeReg = 0;

    for (int t = 0; t < WL_LEVELS; ++t) {
        if (t > 0) {
            if (p0) mixed[s0] = mixu(h[s0]);
            if (p1) mixed[s1] = mixu(h[s1]);
            __syncthreads();
            unsigned hn0 = 0, hn1 = 0;
            if (p0) {
                unsigned msg = 0;
                uint4 aw = *(const uint4*)adjs[s0];
                unsigned bw[4] = {aw.x, aw.y, aw.z, aw.w};
                #pragma unroll
                for (int w = 0; w < 4; ++w) {
                    unsigned bits = bw[w];
                    while (bits) { int l = __ffs(bits) - 1; bits &= bits - 1; msg += mixed[(w << 5) + l]; }
                }
                hn0 = mixu(h[s0] * 0x9E3779B1u + msg);
            }
            if (p1) {
                unsigned msg = 0;
                uint4 aw = *(const uint4*)adjs[s1];
                unsigned bw[4] = {aw.x, aw.y, aw.z, aw.w};
                #pragma unroll
                for (int w = 0; w < 4; ++w) {
                    unsigned bits = bw[w];
                    while (bits) { int l = __ffs(bits) - 1; bits &= bits - 1; msg += mixed[(w << 5) + l]; }
                }
                hn1 = mixu(h[s1] * 0x9E3779B1u + msg);
            }
            __syncthreads();
            if (p0) h[s0] = hn0;
            if (p1) h[s1] = hn1;
            __syncthreads();
        }

        const unsigned hv0 = p0 ? h[s0] : 0u;
        const unsigned hv1 = p1 ? h[s1] : 0u;
        const unsigned* hrow = &hf_s[t * FILTERS * FNODES];
        if (p0) {
            #pragma unroll
            for (int f = 0; f < FILTERS; ++f) {
                unsigned fm = fmb[f], c = 0;
                #pragma unroll
                for (int m = 0; m < FNODES; ++m)
                    c += (unsigned)((hv0 == hrow[f * FNODES + m]) & ((fm >> m) & 1u));
                crossReg[f] += c;
            }
        }
        if (p1) {
            #pragma unroll
            for (int f = 0; f < FILTERS; ++f) {
                unsigned fm = fmb[f], c = 0;
                #pragma unroll
                for (int m = 0; m < FNODES; ++m)
                    c += (unsigned)((hv1 == hrow[f * FNODES + m]) & ((fm >> m) & 1u));
                crossReg[f] += c;
            }
        }
        {   // self_e: scan h[0..S) via uint4 reads + scalar tail
            unsigned ce = 0;
            const int quads = S >> 2;
            const uint4* h4 = (const uint4*)h;
            for (int q = 0; q < quads; ++q) {
                uint4 hh = h4[q];
                if (p0) ce += (unsigned)(hh.x == hv0) + (unsigned)(hh.y == hv0)
                            + (unsigned)(hh.z == hv0) + (unsigned)(hh.w == hv0);
                if (p1) ce += (unsigned)(hh.x == hv1) + (unsigned)(hh.y == hv1)
                            + (unsigned)(hh.z == hv1) + (unsigned)(hh.w == hv1);
            }
            for (int l = quads << 2; l < S; ++l) {
                unsigned hl = h[l];
                if (p0) ce += (unsigned)(hl == hv0);
                if (p1) ce += (unsigned)(hl == hv1);
            }
            selfeReg += ce;
        }
        __syncthreads();
    }

    // ---- wave reduction + output ----
    #pragma unroll
    for (int f = 0; f < FILTERS; ++f) {
        unsigned v = crossReg[f];
        for (int o = 32; o > 0; o >>= 1) v += __shfl_down(v, o, 64);
        crossReg[f] = v;
    }
    {
        unsigned v = selfeReg;
        for (int o = 32; o > 0; o >>= 1) v += __shfl_down(v, o, 64);
        selfeReg = v;
    }
    if (lane == 0) {
        #pragma unroll
        for (int f = 0; f < FILTERS; ++f) cross_sh[f] = crossReg[f];
        selfe_sh = selfeReg;
    }
    __syncthreads();
    if (lane < FILTERS) {
        float se = (float)selfe_sh;
        float sf = selff_s[lane];
        float denom = sqrtf(se * sf);
        float v = (denom > 0.f) ? ((float)cross_sh[lane] / denom) : 0.f;
        out[(size_t)i * FILTERS + lane] = v;
    }
}

extern "C" void kernel_launch(void* const* d_in, const int* in_sizes, int n_in,
                              void* d_out, int out_size, void* d_ws, size_t ws_size,
                              hipStream_t stream) {
    const float* x  = (const float*)d_in[0];
    const int*   ei = (const int*)d_in[1];
    // d_in[2] = batch (unused: single graph)
    const float* A  = (const float*)d_in[3];
    const float* X  = (const float*)d_in[4];
    float* out = (float*)d_out;
    int E2 = in_sizes[1] / 2;   // directed edge count (both directions present)

    char* ws = (char*)d_ws;
    const size_t ADJ_BYTES = (size_t)N_NODES * WORDS * sizeof(u64); // 512 KB
    u64* Adense = (u64*)(ws);
    u64* r2     = (u64*)(ws + ADJ_BYTES);
    unsigned* hfg    = (unsigned*)(ws + 2 * ADJ_BYTES);
    unsigned* fmbg   = (unsigned*)(ws + 2 * ADJ_BYTES + 4096);
    float*    selfg  = (float*)  (ws + 2 * ADJ_BYTES + 4096 + 256);

    build_rows_kernel<<<N_NODES, 64, 0, stream>>>(ei, E2, Adense, A, X, hfg, fmbg, selfg);
    r2_kernel<<<N_NODES, 64, 0, stream>>>(Adense, r2);
    ego_kernel<<<N_NODES, 64, 0, stream>>>(x, Adense, r2, hfg, fmbg, selfg, out);
}

// Round 7
// 148.842 us; speedup vs baseline: 1.1737x; 1.1737x over previous
//
#include <hip/hip_runtime.h>
#include <hip/hip_bf16.h>
#include <stdint.h>

#define N_NODES 2048
#define WORDS   32          // 2048/64 bitset words per row
#define LABELS  16
#define FILTERS 16
#define FNODES  8
#define MAX_EGO 128
#define WL_LEVELS 4

typedef unsigned long long u64;

__device__ __forceinline__ unsigned mixu(unsigned h) {
    h ^= h >> 16; h *= 0x7FEB352Du;
    h ^= h >> 15; h *= 0x846CA68Bu;
    h ^= h >> 16;
    return h;
}

// K1: edge-list atomics build Adense (memset'd beforehand). Last block computes
// the filter-graph WL hashes / masks / self_f.
__global__ void __launch_bounds__(64)
build_adj_kernel(const int* __restrict__ ei, int E2, u64* __restrict__ Adense,
                 const float* __restrict__ Af, const float* __restrict__ Xf,
                 unsigned* __restrict__ hfg, unsigned* __restrict__ fmbg,
                 float* __restrict__ selfg) {
    const int lane = threadIdx.x;
    if ((int)blockIdx.x < (int)gridDim.x - 1) {
        int e = blockIdx.x * 64 + lane;
        if (e < E2) {
            int s = ei[e], d = ei[E2 + e];
            atomicOr(&Adense[(size_t)s * WORDS + (d >> 6)], 1ull << (d & 63));
            atomicOr(&Adense[(size_t)d * WORDS + (s >> 6)], 1ull << (s & 63));
        }
        return;
    }
    if (lane >= FILTERS) return;
    // ---- filters: CC mask, labels, 4 WL levels, self_f -> global ws ----
    int f = lane;
    const float* Aff = Af + (size_t)f * FNODES * FNODES;
    unsigned row[FNODES];
    for (int m = 0; m < FNODES; ++m) {
        unsigned r = 0;
        for (int j = 0; j < FNODES; ++j)
            if (Aff[m * FNODES + j] > 0.f) r |= 1u << j;
        row[m] = r;
    }
    const float* Xff = Xf + (size_t)f * FNODES * LABELS;
    unsigned lab[FNODES];
    for (int m = 0; m < FNODES; ++m) {
        const float* xr = Xff + m * LABELS;
        float best = xr[0]; int bi = 0;
        for (int c = 1; c < LABELS; ++c) { float v = xr[c]; if (v > best) { best = v; bi = c; } }
        lab[m] = (unsigned)(bi + 1);
    }
    int lbl[FNODES];
    for (int m = 0; m < FNODES; ++m) lbl[m] = m;
    for (int it = 0; it < FNODES; ++it) {
        int nb[FNODES];
        for (int m = 0; m < FNODES; ++m) {
            int mn = FNODES;
            for (int j = 0; j < FNODES; ++j)
                if ((row[m] >> j) & 1) mn = min(mn, lbl[j]);
            nb[m] = mn;
        }
        for (int m = 0; m < FNODES; ++m) lbl[m] = min(lbl[m], nb[m]);
    }
    int cnt[FNODES];
    for (int m = 0; m < FNODES; ++m) {
        int c = 0;
        for (int j = 0; j < FNODES; ++j) c += (lbl[j] == lbl[m]);
        cnt[m] = c;
    }
    int best = 0;
    for (int m = 1; m < FNODES; ++m) if (cnt[m] > cnt[best]) best = m;
    unsigned fm = 0;
    for (int m = 0; m < FNODES; ++m) if (lbl[m] == lbl[best]) fm |= 1u << m;
    fmbg[f] = fm;
    unsigned brow[FNODES];
    for (int m = 0; m < FNODES; ++m) brow[m] = ((fm >> m) & 1) ? (row[m] & fm) : 0u;
    unsigned hh[FNODES];
    for (int m = 0; m < FNODES; ++m) hh[m] = mixu(lab[m]);
    float sf = 0.f;
    for (int t = 0; t < WL_LEVELS; ++t) {
        if (t > 0) {
            unsigned mx[FNODES], nh[FNODES];
            for (int m = 0; m < FNODES; ++m) mx[m] = mixu(hh[m]);
            for (int m = 0; m < FNODES; ++m) {
                unsigned msg = 0;
                for (int j = 0; j < FNODES; ++j)
                    if ((brow[m] >> j) & 1) msg += mx[j];
                nh[m] = mixu(hh[m] * 0x9E3779B1u + msg);
            }
            for (int m = 0; m < FNODES; ++m) hh[m] = nh[m];
        }
        for (int m = 0; m < FNODES; ++m)
            hfg[t * FILTERS * FNODES + f * FNODES + m] = hh[m];
        int c = 0;
        for (int m = 0; m < FNODES; ++m) if ((fm >> m) & 1)
            for (int j = 0; j < FNODES; ++j) if ((fm >> j) & 1) c += (hh[m] == hh[j]);
        sf += (float)c;
    }
    selfg[f] = sf;
}

// K2: r2[i] = (I|A)^2 row i.
__global__ void __launch_bounds__(64)
r2_kernel(const u64* __restrict__ Adense, u64* __restrict__ r2) {
    const int i = blockIdx.x;
    const int lane = threadIdx.x;
    const int w = lane & 31, hwp = lane >> 5;
    __shared__ u64 arow[WORDS];
    if (lane < WORDS) arow[lane] = Adense[(size_t)i * WORDS + lane];
    __syncthreads();
    u64 acc = 0;
    if (hwp == 0) {
        acc = arow[w];
        if ((i >> 6) == w) acc |= 1ull << (i & 63);
    }
    for (int w2 = hwp; w2 < WORDS; w2 += 2) {
        u64 bits = arow[w2];
        while (bits) {
            int b = __ffsll(bits) - 1;
            bits &= bits - 1;
            acc |= Adense[(size_t)((w2 << 6) + b) * WORDS + w];
        }
    }
    acc |= __shfl_xor(acc, 32, 64);
    if (hwp == 0) r2[(size_t)i * WORDS + w] = acc;
}

// K3: TWO waves per seed (128 threads). Hop 3 fused; compact adjacency; 4 WL levels.
__global__ void __launch_bounds__(128)
ego_kernel(const float* __restrict__ x,
           const u64* __restrict__ Adense,
           const u64* __restrict__ r2,
           const unsigned* __restrict__ hfg, const unsigned* __restrict__ fmbg,
           const float* __restrict__ selfg, float* __restrict__ out) {
    const int i   = blockIdx.x;
    const int tid = threadIdx.x;       // 0..127
    const int wid = tid >> 6;          // wave id 0/1
    const int q   = tid >> 5;          // quarter-wave 0..3
    const int w   = tid & 31;          // bitset word index

    __shared__ u64 arow[WORDS];
    __shared__ u64 mmpart[2][WORDS];   // per-wave hop3 partials
    __shared__ u64 mmask[WORDS];
    __shared__ unsigned pfx[WORDS];
    __shared__ unsigned members[MAX_EGO];
    __shared__ __align__(16) unsigned h[MAX_EGO];
    __shared__ unsigned mixed[MAX_EGO];
    __shared__ __align__(16) unsigned adjs[MAX_EGO][4];
    __shared__ unsigned hf_s[WL_LEVELS * FILTERS * FNODES];
    __shared__ unsigned fmb[FILTERS];
    __shared__ float    selff_s[FILTERS];
    __shared__ unsigned cross_w[2][FILTERS];
    __shared__ unsigned selfe_w[2];
    __shared__ int Scnt;

    for (int t = tid; t < WL_LEVELS * FILTERS * FNODES; t += 128) hf_s[t] = hfg[t];
    if (tid < FILTERS) { fmb[tid] = fmbg[tid]; selff_s[tid] = selfg[tid]; }
    #pragma unroll
    for (int t = tid; t < MAX_EGO * 4; t += 128) ((unsigned*)adjs)[t] = 0;
    if (tid < WORDS) arow[tid] = Adense[(size_t)i * WORDS + tid];
    __syncthreads();

    // ---- hop 3: 4 quarter-waves split neighbor set; merge shfl + LDS ----
    {
        u64 v = (q == 0) ? r2[(size_t)i * WORDS + w] : 0ull;
        for (int w2 = q; w2 < WORDS; w2 += 4) {
            u64 bits = arow[w2];
            while (bits) {
                int b = __ffsll(bits) - 1;
                bits &= bits - 1;
                v |= r2[(size_t)((w2 << 6) + b) * WORDS + w];
            }
        }
        v |= __shfl_xor(v, 32, 64);          // merge the wave's two quarters
        mmpart[wid][w] = v;                  // both halves write same value
    }
    __syncthreads();

    // ---- member mask trim (all 4 quarter-waves compute identically) ----
    int S;
    {
        u64 v = mmpart[0][w] | mmpart[1][w];
        int seedw = i >> 6;
        u64 seedbit = 1ull << (i & 63);
        if (w == seedw) v &= ~seedbit;
        int pc = __popcll(v);
        int incl = pc;
        for (int d = 1; d < 32; d <<= 1) {
            int t2 = __shfl_up(incl, d, 32);
            if (w >= d) incl += t2;
        }
        int excl = incl - pc;
        const int keep = MAX_EGO - 1;
        if (excl >= keep) {
            v = 0;
        } else {
            int allow = keep - excl;
            while (pc > allow) {
                v &= ~(1ull << (63 - __clzll(v)));
                --pc;
            }
        }
        if (w == seedw) v |= seedbit;
        mmask[w] = v;
        int pc2 = __popcll(v);
        int incl2 = pc2;
        for (int d = 1; d < 32; d <<= 1) {
            int t2 = __shfl_up(incl2, d, 32);
            if (w >= d) incl2 += t2;
        }
        int ex2 = incl2 - pc2;
        pfx[w] = (unsigned)ex2;
        if (tid == 31) Scnt = incl2;
        u64 vv = v;
        int r = 0;
        while (vv) {
            int b = __ffsll(vv) - 1;
            vv &= vv - 1;
            members[ex2 + r] = (unsigned)((w << 6) + b);   // all quarters: same data
            ++r;
        }
    }
    __syncthreads();
    S = Scnt;
    const bool pp = (tid < S);

    // ---- initial WL labels (argmax16, first-max tie-break), one slot/thread ----
    if (pp) {
        const float4* xr = (const float4*)(x + (size_t)members[tid] * LABELS);
        float4 a0 = xr[0], a1 = xr[1], a2 = xr[2], a3 = xr[3];
        float vv[16] = {a0.x,a0.y,a0.z,a0.w,a1.x,a1.y,a1.z,a1.w,
                        a2.x,a2.y,a2.z,a2.w,a3.x,a3.y,a3.z,a3.w};
        float best = vv[0]; int bi = 0;
        #pragma unroll
        for (int c = 1; c < 16; ++c) { if (vv[c] > best) { best = vv[c]; bi = c; } }
        h[tid] = mixu((unsigned)(bi + 1));
    }

    // ---- compact ego adjacency: quarter-wave per slot, 4-deep load batch ----
    {
        const u64 mw = mmask[w];
        const unsigned base = pfx[w];
        for (int t = q; t < S; t += 16) {
            int t1 = t + 4, t2 = t + 8, t3 = t + 12;
            u64 v0 = Adense[(size_t)members[t] * WORDS + w] & mw;
            u64 v1 = (t1 < S) ? (Adense[(size_t)members[t1] * WORDS + w] & mw) : 0ull;
            u64 v2 = (t2 < S) ? (Adense[(size_t)members[t2] * WORDS + w] & mw) : 0ull;
            u64 v3 = (t3 < S) ? (Adense[(size_t)members[t3] * WORDS + w] & mw) : 0ull;
            while (v0) {
                int b = __ffsll(v0) - 1; v0 &= v0 - 1;
                int slot = (int)base + __popcll(mw & ((1ull << b) - 1));
                atomicOr(&adjs[t][slot >> 5], 1u << (slot & 31));
            }
            while (v1) {
                int b = __ffsll(v1) - 1; v1 &= v1 - 1;
                int slot = (int)base + __popcll(mw & ((1ull << b) - 1));
                atomicOr(&adjs[t1][slot >> 5], 1u << (slot & 31));
            }
            while (v2) {
                int b = __ffsll(v2) - 1; v2 &= v2 - 1;
                int slot = (int)base + __popcll(mw & ((1ull << b) - 1));
                atomicOr(&adjs[t2][slot >> 5], 1u << (slot & 31));
            }
            while (v3) {
                int b = __ffsll(v3) - 1; v3 &= v3 - 1;
                int slot = (int)base + __popcll(mw & ((1ull << b) - 1));
                atomicOr(&adjs[t3][slot >> 5], 1u << (slot & 31));
            }
        }
    }
    __syncthreads();

    // ---- 4 WL levels: refine + cross/self accumulate (one slot/thread) ----
    unsigned crossReg[FILTERS];
    #pragma unroll
    for (int f = 0; f < FILTERS; ++f) crossReg[f] = 0;
    unsigned selfeReg = 0;

    for (int t = 0; t < WL_LEVELS; ++t) {
        if (t > 0) {
            if (pp) mixed[tid] = mixu(h[tid]);
            __syncthreads();
            unsigned hn = 0;
            if (pp) {
                unsigned msg = 0;
                uint4 aw = *(const uint4*)adjs[tid];
                unsigned bw[4] = {aw.x, aw.y, aw.z, aw.w};
                #pragma unroll
                for (int ww = 0; ww < 4; ++ww) {
                    unsigned bits = bw[ww];
                    while (bits) { int l = __ffs(bits) - 1; bits &= bits - 1; msg += mixed[(ww << 5) + l]; }
                }
                hn = mixu(h[tid] * 0x9E3779B1u + msg);
            }
            __syncthreads();
            if (pp) h[tid] = hn;
            __syncthreads();
        }

        const unsigned hv = pp ? h[tid] : 0u;
        const unsigned* hrow = &hf_s[t * FILTERS * FNODES];
        if (pp) {
            #pragma unroll
            for (int f = 0; f < FILTERS; ++f) {
                unsigned fm = fmb[f], c = 0;
                #pragma unroll
                for (int m = 0; m < FNODES; ++m)
                    c += (unsigned)((hv == hrow[f * FNODES + m]) & ((fm >> m) & 1u));
                crossReg[f] += c;
            }
            // self_e: scan h[0..S) via uint4 reads + scalar tail
            unsigned ce = 0;
            const int quads = S >> 2;
            const uint4* h4 = (const uint4*)h;
            for (int qq = 0; qq < quads; ++qq) {
                uint4 hh = h4[qq];
                ce += (unsigned)(hh.x == hv) + (unsigned)(hh.y == hv)
                    + (unsigned)(hh.z == hv) + (unsigned)(hh.w == hv);
            }
            for (int l = quads << 2; l < S; ++l) ce += (unsigned)(h[l] == hv);
            selfeReg += ce;
        }
        __syncthreads();
    }

    // ---- reduction: per-wave shfl, then combine the two waves via LDS ----
    #pragma unroll
    for (int f = 0; f < FILTERS; ++f) {
        unsigned v = crossReg[f];
        for (int o = 32; o > 0; o >>= 1) v += __shfl_down(v, o, 64);
        crossReg[f] = v;
    }
    {
        unsigned v = selfeReg;
        for (int o = 32; o > 0; o >>= 1) v += __shfl_down(v, o, 64);
        selfeReg = v;
    }
    if ((tid & 63) == 0) {
        #pragma unroll
        for (int f = 0; f < FILTERS; ++f) cross_w[wid][f] = crossReg[f];
        selfe_w[wid] = selfeReg;
    }
    __syncthreads();
    if (tid < FILTERS) {
        float se = (float)(selfe_w[0] + selfe_w[1]);
        float sf = selff_s[tid];
        float denom = sqrtf(se * sf);
        unsigned cr = cross_w[0][tid] + cross_w[1][tid];
        float v = (denom > 0.f) ? ((float)cr / denom) : 0.f;
        out[(size_t)i * FILTERS + tid] = v;
    }
}

extern "C" void kernel_launch(void* const* d_in, const int* in_sizes, int n_in,
                              void* d_out, int out_size, void* d_ws, size_t ws_size,
                              hipStream_t stream) {
    const float* x  = (const float*)d_in[0];
    const int*   ei = (const int*)d_in[1];
    // d_in[2] = batch (unused: single graph)
    const float* A  = (const float*)d_in[3];
    const float* X  = (const float*)d_in[4];
    float* out = (float*)d_out;
    int E2 = in_sizes[1] / 2;   // directed edge count (both directions present)

    char* ws = (char*)d_ws;
    const size_t ADJ_BYTES = (size_t)N_NODES * WORDS * sizeof(u64); // 512 KB
    u64* Adense = (u64*)(ws);
    u64* r2     = (u64*)(ws + ADJ_BYTES);
    unsigned* hfg    = (unsigned*)(ws + 2 * ADJ_BYTES);
    unsigned* fmbg   = (unsigned*)(ws + 2 * ADJ_BYTES + 4096);
    float*    selfg  = (float*)  (ws + 2 * ADJ_BYTES + 4096 + 256);

    hipMemsetAsync(Adense, 0, ADJ_BYTES, stream);
    int nbE = (E2 + 63) / 64;
    build_adj_kernel<<<nbE + 1, 64, 0, stream>>>(ei, E2, Adense, A, X, hfg, fmbg, selfg);
    r2_kernel<<<N_NODES, 64, 0, stream>>>(Adense, r2);
    ego_kernel<<<N_NODES, 128, 0, stream>>>(x, Adense, r2, hfg, fmbg, selfg, out);
}